// Round 1
// 1428.495 us; speedup vs baseline: 1.7561x; 1.7561x over previous
//
#include <hip/hip_runtime.h>
#include <cstdint>
#include <cstddef>

// B=4, S=2048, D=512, H=8, DK=64.
// Outputs: out [B,S,D] then attention [B,H,S,S], both fp32, concatenated in d_out.
//
// organic bias is uniform across the key axis per query row -> cancels in softmax.
//
// Pipeline:
//   proj(Q/K/V)  -> head layout [BH,S,DK]
//   scores       -> raw masked scaled scores into attn region (written once)
//   mlreduce     -> per-row max m and 1/sum(exp) into scratch (out region, overwritten later)
//   context      -> reads raw scores, normalizes IN-PLACE (final attention output),
//                   and accumulates P@V into C
//   proj(out)    -> final projection, overwrites the m/l scratch
//
// ws layout (floats): Q[BH,S,DK] | K | V | C[B,S,D]  = 64 MB (same as before).

static constexpr int B  = 4;
static constexpr int S  = 2048;
static constexpr int D  = 512;
static constexpr int H  = 8;
static constexpr int DK = 64;
static constexpr int N  = B * S;   // 8192
static constexpr int BH = B * H;   // 32

__device__ __forceinline__ float f4c(const float4& v, int j) {
  return j == 0 ? v.x : j == 1 ? v.y : j == 2 ? v.z : v.w;
}

__device__ __forceinline__ void fma4x4(float (&acc)[4][4], const float4 a, const float4 b) {
  const float av[4] = {a.x, a.y, a.z, a.w};
  const float bv[4] = {b.x, b.y, b.z, b.w};
#pragma unroll
  for (int i = 0; i < 4; ++i)
#pragma unroll
    for (int j = 0; j < 4; ++j) acc[i][j] = fmaf(av[i], bv[j], acc[i][j]);
}

// ---------------- Y = X @ W^T + bias. 64x128 tile, 8x(2x4) per thread -------
__global__ __launch_bounds__(256, 4) void proj_kernel(
    const float* __restrict__ X, const float* __restrict__ W,
    const float* __restrict__ bias, float* __restrict__ Y, int head_layout)
{
  __shared__ float As[32][64];    // As[k][row]
  __shared__ float Bs[32][128];   // Bs[k][col]
  const int tid = threadIdx.x;
  const int tx = tid & 15, ty = tid >> 4;
  const int row0 = blockIdx.x * 64, col0 = blockIdx.y * 128;

  const int brq = (tid & 31) * 4;        // B tile row-quad 0..124
  const int bcq = (tid >> 5) * 4;        // B tile col-quad 0..28
  const int arq = (tid & 15) * 4;        // A tile row-quad 0..60
  const int acq = ((tid >> 4) & 7) * 4;  // A tile col-quad 0..28

  float acc[2][4][4] = {};
  const int ra = ty * 4, ca = tx * 4;

  for (int kc = 0; kc < D; kc += 32) {
    float4 wr[4], xr[4];
#pragma unroll
    for (int rr = 0; rr < 4; ++rr)
      wr[rr] = *(const float4*)&W[(size_t)(col0 + brq + rr) * D + kc + bcq];
    if (tid < 128) {
#pragma unroll
      for (int rr = 0; rr < 4; ++rr)
        xr[rr] = *(const float4*)&X[(size_t)(row0 + arq + rr) * D + kc + acq];
    }
    __syncthreads();
#pragma unroll
    for (int j = 0; j < 4; ++j)
      *(float4*)&Bs[bcq + j][brq] =
          make_float4(f4c(wr[0], j), f4c(wr[1], j), f4c(wr[2], j), f4c(wr[3], j));
    if (tid < 128) {
#pragma unroll
      for (int j = 0; j < 4; ++j)
        *(float4*)&As[acq + j][arq] =
            make_float4(f4c(xr[0], j), f4c(xr[1], j), f4c(xr[2], j), f4c(xr[3], j));
    }
    __syncthreads();
#pragma unroll 4
    for (int k = 0; k < 32; ++k) {
      const float4 av = *(const float4*)&As[k][ra];
      const float4 b0 = *(const float4*)&Bs[k][ca];
      const float4 b1 = *(const float4*)&Bs[k][64 + ca];
      fma4x4(acc[0], av, b0);
      fma4x4(acc[1], av, b1);
    }
  }

  const int oc0 = col0 + ca;
  const float4 bi0 = *(const float4*)&bias[oc0];
  const float4 bi1 = *(const float4*)&bias[oc0 + 64];
#pragma unroll
  for (int i = 0; i < 4; ++i) {
    const int row = row0 + ra + i;
    const int bb = row >> 11, ss = row & (S - 1);
#pragma unroll
    for (int oh = 0; oh < 2; ++oh) {
      const int oc = oc0 + oh * 64;
      size_t dst;
      if (head_layout) {
        dst = ((size_t)(bb * H + (oc >> 6)) * S + ss) * DK + (oc & 63);
      } else {
        dst = (size_t)row * D + oc;
      }
      const float4 bi = oh ? bi1 : bi0;
      *(float4*)&Y[dst] = make_float4(acc[oh][i][0] + bi.x, acc[oh][i][1] + bi.y,
                                      acc[oh][i][2] + bi.z, acc[oh][i][3] + bi.w);
    }
  }
}

// ---------------- raw scores: attn[bh,q,k] = mask ? (Q.K)/8 : -1e9 ----------
// 128x128 tile per block, 8x8 per thread (split quads at +64 for bank-friendly b128).
__global__ __launch_bounds__(256, 2) void scores_kernel(
    const float* __restrict__ Q, const float* __restrict__ Kp,
    const int* __restrict__ mask, float* __restrict__ attn)
{
  __shared__ float Qs[64][128];   // Qs[d][q]
  __shared__ float Ks[64][128];   // Ks[d][k]
  const int tid = threadIdx.x;
  const int tx = tid & 15, ty = tid >> 4;
  const int q0 = blockIdx.x * 128, k0 = blockIdx.y * 128;
  const int bh = (int)blockIdx.z, b = bh >> 3;
  const float* __restrict__ Qh = Q + (size_t)bh * S * DK;
  const float* __restrict__ Kh = Kp + (size_t)bh * S * DK;

  // stage 128x64 tiles transposed via 4x4 register transpose (measured conflict-free pattern)
  const int rq4 = (tid & 31) * 4;        // row-quad 0..124
  const int ch  = (tid >> 5) * 4;        // col-quad 0..28
#pragma unroll
  for (int half = 0; half < 64; half += 32) {
    const int cd4 = ch + half;
    float4 qr[4], kr[4];
#pragma unroll
    for (int rr = 0; rr < 4; ++rr) {
      qr[rr] = *(const float4*)&Qh[(size_t)(q0 + rq4 + rr) * DK + cd4];
      kr[rr] = *(const float4*)&Kh[(size_t)(k0 + rq4 + rr) * DK + cd4];
    }
#pragma unroll
    for (int j = 0; j < 4; ++j) {
      *(float4*)&Qs[cd4 + j][rq4] =
          make_float4(f4c(qr[0], j), f4c(qr[1], j), f4c(qr[2], j), f4c(qr[3], j));
      *(float4*)&Ks[cd4 + j][rq4] =
          make_float4(f4c(kr[0], j), f4c(kr[1], j), f4c(kr[2], j), f4c(kr[3], j));
    }
  }
  __syncthreads();

  float acc[2][2][4][4] = {};   // [qhalf][khalf][qi][kj]
  const int qa = ty * 4, ka = tx * 4;
#pragma unroll 8
  for (int d = 0; d < 64; ++d) {
    const float4 a0 = *(const float4*)&Qs[d][qa];
    const float4 a1 = *(const float4*)&Qs[d][64 + qa];
    const float4 b0 = *(const float4*)&Ks[d][ka];
    const float4 b1 = *(const float4*)&Ks[d][64 + ka];
    fma4x4(acc[0][0], a0, b0); fma4x4(acc[0][1], a0, b1);
    fma4x4(acc[1][0], a1, b0); fma4x4(acc[1][1], a1, b1);
  }

  int mk[2][4];
#pragma unroll
  for (int kh = 0; kh < 2; ++kh)
#pragma unroll
    for (int j = 0; j < 4; ++j)
      mk[kh][j] = mask[b * S + k0 + kh * 64 + ka + j];

#pragma unroll
  for (int qh = 0; qh < 2; ++qh)
#pragma unroll
    for (int i = 0; i < 4; ++i) {
      const int q = q0 + qh * 64 + qa + i;
      float* __restrict__ dst = &attn[((size_t)bh * S + q) * S + k0];
#pragma unroll
      for (int kh = 0; kh < 2; ++kh) {
        float4 st;
        st.x = mk[kh][0] ? acc[qh][kh][i][0] * 0.125f : -1e9f;
        st.y = mk[kh][1] ? acc[qh][kh][i][1] * 0.125f : -1e9f;
        st.z = mk[kh][2] ? acc[qh][kh][i][2] * 0.125f : -1e9f;
        st.w = mk[kh][3] ? acc[qh][kh][i][3] * 0.125f : -1e9f;
        *(float4*)&dst[kh * 64 + ka] = st;
      }
    }
}

// ---------------- per-row max and 1/sum(exp) over 2048 cols ----------------
__global__ __launch_bounds__(256) void mlreduce_kernel(
    const float* __restrict__ attn, float* __restrict__ Mrow, float* __restrict__ Linv)
{
  const int row = (int)blockIdx.x;
  const float* __restrict__ p = attn + (size_t)row * S;
  const int tid = threadIdx.x;
  const float4 a = *(const float4*)&p[tid * 4];
  const float4 c = *(const float4*)&p[1024 + tid * 4];

  float m = fmaxf(fmaxf(fmaxf(a.x, a.y), fmaxf(a.z, a.w)),
                  fmaxf(fmaxf(c.x, c.y), fmaxf(c.z, c.w)));
#pragma unroll
  for (int off = 32; off > 0; off >>= 1) m = fmaxf(m, __shfl_xor(m, off));
  __shared__ float redm[4], reds[4];
  const int wv = tid >> 6, ln = tid & 63;
  if (ln == 0) redm[wv] = m;
  __syncthreads();
  m = fmaxf(fmaxf(redm[0], redm[1]), fmaxf(redm[2], redm[3]));

  float s = __expf(a.x - m) + __expf(a.y - m) + __expf(a.z - m) + __expf(a.w - m)
          + __expf(c.x - m) + __expf(c.y - m) + __expf(c.z - m) + __expf(c.w - m);
#pragma unroll
  for (int off = 32; off > 0; off >>= 1) s += __shfl_xor(s, off);
  if (ln == 0) reds[wv] = s;
  __syncthreads();
  if (tid == 0) {
    const float l = reds[0] + reds[1] + reds[2] + reds[3];
    Mrow[row] = m;
    Linv[row] = 1.0f / l;
  }
}

// ---------------- context: normalize attn in-place + C = P@V ----------------
// Block: 128 q rows x full DK, k-loop in 64-wide tiles. Reads raw scores, writes
// normalized attention (the final output) back in place, accumulates P@V.
__global__ __launch_bounds__(256, 3) void context_kernel(
    float* __restrict__ attn, const float* __restrict__ V,
    const float* __restrict__ Mrow, const float* __restrict__ Linv,
    float* __restrict__ C)
{
  __shared__ float Ps[64][128];   // Ps[k][q]
  __shared__ float Vs[64][64];    // Vs[k][d]
  const int tid = threadIdx.x;
  const int tx = tid & 15, ty = tid >> 4;
  const int q0 = blockIdx.x * 128;
  const int bh = (int)blockIdx.z, b = bh >> 3, h = bh & 7;
  float* __restrict__ A = attn + (size_t)bh * S * S;
  const float* __restrict__ Vh = V + (size_t)bh * S * DK;

  const int rq4 = (tid & 31) * 4;   // P row-quad 0..124
  const int ch  = (tid >> 5) * 4;   // P col-quad 0..28
  float mr[4], il[4];
#pragma unroll
  for (int rr = 0; rr < 4; ++rr) {
    mr[rr] = Mrow[(size_t)bh * S + q0 + rq4 + rr];
    il[rr] = Linv[(size_t)bh * S + q0 + rq4 + rr];
  }

  float acc[2][4][4] = {};   // [qhalf][qi][dj]
  const int qa = ty * 4, da = tx * 4;

  for (int k0 = 0; k0 < S; k0 += 64) {
    __syncthreads();   // previous iteration's LDS reads done
    // stage P: load raw, normalize, write back in place, transpose into LDS
#pragma unroll
    for (int half = 0; half < 64; half += 32) {
      const int cd4 = ch + half;
      float4 pr[4];
#pragma unroll
      for (int rr = 0; rr < 4; ++rr) {
        float* __restrict__ ap = &A[(size_t)(q0 + rq4 + rr) * S + k0 + cd4];
        float4 v = *(const float4*)ap;
        v.x = __expf(v.x - mr[rr]) * il[rr];
        v.y = __expf(v.y - mr[rr]) * il[rr];
        v.z = __expf(v.z - mr[rr]) * il[rr];
        v.w = __expf(v.w - mr[rr]) * il[rr];
        *(float4*)ap = v;   // final attention output
        pr[rr] = v;
      }
#pragma unroll
      for (int j = 0; j < 4; ++j)
        *(float4*)&Ps[cd4 + j][rq4] =
            make_float4(f4c(pr[0], j), f4c(pr[1], j), f4c(pr[2], j), f4c(pr[3], j));
    }
    // stage V (natural layout, coalesced)
#pragma unroll
    for (int jj = 0; jj < 4; ++jj) {
      const int r = ty + 16 * jj;
      *(float4*)&Vs[r][da] = *(const float4*)&Vh[(size_t)(k0 + r) * DK + da];
    }
    __syncthreads();
#pragma unroll 8
    for (int k = 0; k < 64; ++k) {
      const float4 a0 = *(const float4*)&Ps[k][qa];
      const float4 a1 = *(const float4*)&Ps[k][64 + qa];
      const float4 bv = *(const float4*)&Vs[k][da];
      fma4x4(acc[0], a0, bv);
      fma4x4(acc[1], a1, bv);
    }
  }

#pragma unroll
  for (int qh = 0; qh < 2; ++qh)
#pragma unroll
    for (int i = 0; i < 4; ++i) {
      const int q = q0 + qh * 64 + qa + i;
      *(float4*)&C[((size_t)(b * S + q)) * D + h * DK + da] =
          make_float4(acc[qh][i][0], acc[qh][i][1], acc[qh][i][2], acc[qh][i][3]);
    }
}

extern "C" void kernel_launch(void* const* d_in, const int* in_sizes, int n_in,
                              void* d_out, int out_size, void* d_ws, size_t ws_size,
                              hipStream_t stream)
{
  (void)in_sizes; (void)n_in; (void)out_size; (void)ws_size;
  const float* query = (const float*)d_in[0];
  const float* key   = (const float*)d_in[1];
  const float* value = (const float*)d_in[2];
  const int*   mask  = (const int*)d_in[3];
  // d_in[4] = is_organic (unused: cancels in softmax)
  const float* Wq = (const float*)d_in[5];
  const float* bq = (const float*)d_in[6];
  const float* Wk = (const float*)d_in[7];
  const float* bk = (const float*)d_in[8];
  const float* Wv = (const float*)d_in[9];
  const float* bv = (const float*)d_in[10];
  const float* Wo = (const float*)d_in[11];
  const float* bo = (const float*)d_in[12];
  // d_in[13]=Worg, d_in[14]=borg (unused: cancel in softmax)

  float* out  = (float*)d_out;
  float* attn = out + (size_t)N * D;

  float* Qb = (float*)d_ws;
  float* Kb = Qb + (size_t)N * D;
  float* Vb = Kb + (size_t)N * D;
  float* Cb = Vb + (size_t)N * D;

  // m / 1/l scratch lives in the `out` region (512 KB of 16.8 MB); the final
  // projection overwrites all of `out` afterwards.
  float* Mrow = out;
  float* Linv = out + (size_t)BH * S;

  const dim3 blk(256);
  proj_kernel<<<dim3(N / 64, D / 128), blk, 0, stream>>>(query, Wq, bq, Qb, 1);
  proj_kernel<<<dim3(N / 64, D / 128), blk, 0, stream>>>(key,   Wk, bk, Kb, 1);
  proj_kernel<<<dim3(N / 64, D / 128), blk, 0, stream>>>(value, Wv, bv, Vb, 1);
  scores_kernel<<<dim3(S / 128, S / 128, BH), blk, 0, stream>>>(Qb, Kb, mask, attn);
  mlreduce_kernel<<<dim3(BH * S), blk, 0, stream>>>(attn, Mrow, Linv);
  context_kernel<<<dim3(S / 128, 1, BH), blk, 0, stream>>>(attn, Vb, Mrow, Linv, Cb);
  proj_kernel<<<dim3(N / 64, D / 128), blk, 0, stream>>>(Cb, Wo, bo, out, 0);
}

// Round 2
// 1426.814 us; speedup vs baseline: 1.7582x; 1.0012x over previous
//
#include <hip/hip_runtime.h>
#include <cstdint>
#include <cstddef>

// B=4, S=2048, D=512, H=8, DK=64.
// Outputs: out [B,S,D] then attention [B,H,S,S], both fp32, concatenated in d_out.
//
// organic bias is uniform across the key axis per query row -> cancels in softmax.
//
// Pipeline:
//   proj(Q/K)   -> head layout bf16 hi/lo pairs (for MFMA scores)
//   proj(V)     -> head layout fp32
//   scores      -> MFMA bf16x2 QK^T, masked scaled scores into attn region,
//                  plus per-row per-128-tile (max, sumexp) partials
//   mlreduce    -> merge 16 partials/row -> Mrow, Linv (8 MB read, not 537 MB)
//   context     -> reads raw scores, normalizes IN-PLACE (final attention),
//                  accumulates P@V into C
//   proj(out)   -> final projection
//
// ws (floats-equiv): Qhi|Qlo|Khi|Klo (bf16, 8MB each) | V fp32 16MB | C fp32 16MB = 64 MB.
// scratch in out region (overwritten by final proj): Mp 4MB | Lp 4MB | Mrow | Linv.

static constexpr int B  = 4;
static constexpr int S  = 2048;
static constexpr int D  = 512;
static constexpr int H  = 8;
static constexpr int DK = 64;
static constexpr int N  = B * S;   // 8192
static constexpr int BH = B * H;   // 32
static constexpr int KT = S / 128; // 16 k-tiles per row

typedef __bf16 bf16x8 __attribute__((ext_vector_type(8)));
typedef float  f32x16 __attribute__((ext_vector_type(16)));

__device__ __forceinline__ float f4c(const float4& v, int j) {
  return j == 0 ? v.x : j == 1 ? v.y : j == 2 ? v.z : v.w;
}

__device__ __forceinline__ void fma4x4(float (&acc)[4][4], const float4 a, const float4 b) {
  const float av[4] = {a.x, a.y, a.z, a.w};
  const float bv[4] = {b.x, b.y, b.z, b.w};
#pragma unroll
  for (int i = 0; i < 4; ++i)
#pragma unroll
    for (int j = 0; j < 4; ++j) acc[i][j] = fmaf(av[i], bv[j], acc[i][j]);
}

// round-to-nearest-even fp32 -> bf16 bits (no NaN/overflow concern here)
__device__ __forceinline__ ushort f2bf(float x) {
  uint32_t u = __float_as_uint(x);
  u += 0x7FFFu + ((u >> 16) & 1u);
  return (ushort)(u >> 16);
}

// ---------------- Y = X @ W^T + bias. 64x128 tile, 8x(2x4) per thread -------
// mode 0: flat fp32 -> Yf; mode 1: head-layout fp32 -> Yf;
// mode 2: head-layout bf16 hi/lo -> Yhi/Ylo.
__global__ __launch_bounds__(256, 4) void proj_kernel(
    const float* __restrict__ X, const float* __restrict__ W,
    const float* __restrict__ bias, float* __restrict__ Yf,
    ushort* __restrict__ Yhi, ushort* __restrict__ Ylo, int mode)
{
  __shared__ float As[32][64];    // As[k][row]
  __shared__ float Bs[32][128];   // Bs[k][col]
  const int tid = threadIdx.x;
  const int tx = tid & 15, ty = tid >> 4;
  const int row0 = blockIdx.x * 64, col0 = blockIdx.y * 128;

  const int brq = (tid & 31) * 4;        // B tile row-quad 0..124
  const int bcq = (tid >> 5) * 4;        // B tile col-quad 0..28
  const int arq = (tid & 15) * 4;        // A tile row-quad 0..60
  const int acq = ((tid >> 4) & 7) * 4;  // A tile col-quad 0..28

  float acc[2][4][4] = {};
  const int ra = ty * 4, ca = tx * 4;

  for (int kc = 0; kc < D; kc += 32) {
    float4 wr[4], xr[4];
#pragma unroll
    for (int rr = 0; rr < 4; ++rr)
      wr[rr] = *(const float4*)&W[(size_t)(col0 + brq + rr) * D + kc + bcq];
    if (tid < 128) {
#pragma unroll
      for (int rr = 0; rr < 4; ++rr)
        xr[rr] = *(const float4*)&X[(size_t)(row0 + arq + rr) * D + kc + acq];
    }
    __syncthreads();
#pragma unroll
    for (int j = 0; j < 4; ++j)
      *(float4*)&Bs[bcq + j][brq] =
          make_float4(f4c(wr[0], j), f4c(wr[1], j), f4c(wr[2], j), f4c(wr[3], j));
    if (tid < 128) {
#pragma unroll
      for (int j = 0; j < 4; ++j)
        *(float4*)&As[acq + j][arq] =
            make_float4(f4c(xr[0], j), f4c(xr[1], j), f4c(xr[2], j), f4c(xr[3], j));
    }
    __syncthreads();
#pragma unroll 4
    for (int k = 0; k < 32; ++k) {
      const float4 av = *(const float4*)&As[k][ra];
      const float4 b0 = *(const float4*)&Bs[k][ca];
      const float4 b1 = *(const float4*)&Bs[k][64 + ca];
      fma4x4(acc[0], av, b0);
      fma4x4(acc[1], av, b1);
    }
  }

  const int oc0 = col0 + ca;
  const float4 bi0 = *(const float4*)&bias[oc0];
  const float4 bi1 = *(const float4*)&bias[oc0 + 64];
#pragma unroll
  for (int i = 0; i < 4; ++i) {
    const int row = row0 + ra + i;
    const int bb = row >> 11, ss = row & (S - 1);
#pragma unroll
    for (int oh = 0; oh < 2; ++oh) {
      const int oc = oc0 + oh * 64;
      const float4 bi = oh ? bi1 : bi0;
      float v[4] = {acc[oh][i][0] + bi.x, acc[oh][i][1] + bi.y,
                    acc[oh][i][2] + bi.z, acc[oh][i][3] + bi.w};
      if (mode == 0) {
        *(float4*)&Yf[(size_t)row * D + oc] = make_float4(v[0], v[1], v[2], v[3]);
      } else {
        const size_t dst = ((size_t)(bb * H + (oc >> 6)) * S + ss) * DK + (oc & 63);
        if (mode == 1) {
          *(float4*)&Yf[dst] = make_float4(v[0], v[1], v[2], v[3]);
        } else {
          ushort h[4], lo[4];
#pragma unroll
          for (int j = 0; j < 4; ++j) {
            h[j] = f2bf(v[j]);
            const float hf = __uint_as_float((uint32_t)h[j] << 16);
            lo[j] = f2bf(v[j] - hf);
          }
          *(ushort4*)&Yhi[dst] = make_ushort4(h[0], h[1], h[2], h[3]);
          *(ushort4*)&Ylo[dst] = make_ushort4(lo[0], lo[1], lo[2], lo[3]);
        }
      }
    }
  }
}

// ---------------- MFMA bf16x2 scores + per-tile m/l partials ----------------
// attn[bh,q,k] = mask ? (Q.K)/8 : -1e9 ; Mp/Lp[row][ktile] = (max, sum exp(.-max))
// 128x128 tile per block, 4 waves in 2x2 grid, each wave 64x64 via 2x2 MFMA 32x32x16.
__global__ __launch_bounds__(256, 2) void scores_kernel(
    const ushort* __restrict__ Qh, const ushort* __restrict__ Ql,
    const ushort* __restrict__ Kh, const ushort* __restrict__ Kl,
    const int* __restrict__ mask, float* __restrict__ attn,
    float* __restrict__ Mp, float* __restrict__ Lp)
{
  __shared__ ushort sQh[128 * 64], sQl[128 * 64];   // [row][k] bf16, XOR-swizzled
  __shared__ ushort sKh[128 * 64], sKl[128 * 64];
  const int tid = threadIdx.x;
  const int q0 = blockIdx.x * 128, k0 = blockIdx.y * 128;
  const int bh = (int)blockIdx.z, b = bh >> 3;

  // stage 4 [128][64]-bf16 tiles; row byte-stride 128 = bank period -> swizzle
  auto stage = [&](const ushort* __restrict__ src, ushort* dst) {
#pragma unroll
    for (int i = tid; i < 1024; i += 256) {   // 1024 chunks of 8 bf16 (16 B)
      const int row = i >> 3, kg = i & 7;
      const float4 v = *(const float4*)&src[(size_t)row * DK + kg * 8];
      *(float4*)((char*)dst + ((row * 128 + kg * 16) ^ ((row & 7) << 4))) = v;
    }
  };
  stage(Qh + ((size_t)bh * S + q0) * DK, sQh);
  stage(Ql + ((size_t)bh * S + q0) * DK, sQl);
  stage(Kh + ((size_t)bh * S + k0) * DK, sKh);
  stage(Kl + ((size_t)bh * S + k0) * DK, sKl);
  __syncthreads();

  const int wid = tid >> 6, lane = tid & 63;
  const int wm = wid >> 1, wn = wid & 1;      // wave 2x2 grid over 128x128
  const int g = lane >> 5, l31 = lane & 31;

  f32x16 acc[2][2] = {};
#pragma unroll
  for (int ks = 0; ks < 4; ++ks) {            // DK=64 in 4 steps of K=16
    const int kb = (ks * 2 + g) * 16;         // byte offset of this lane-group's 8 bf16
    bf16x8 aH[2], aL[2], bHf[2], bLf[2];
#pragma unroll
    for (int mq = 0; mq < 2; ++mq) {
      const int row = wm * 64 + mq * 32 + l31;
      const int byo = (row * 128 + kb) ^ ((row & 7) << 4);
      aH[mq] = *(const bf16x8*)((const char*)sQh + byo);
      aL[mq] = *(const bf16x8*)((const char*)sQl + byo);
    }
#pragma unroll
    for (int nq = 0; nq < 2; ++nq) {
      const int row = wn * 64 + nq * 32 + l31;
      const int byo = (row * 128 + kb) ^ ((row & 7) << 4);
      bHf[nq] = *(const bf16x8*)((const char*)sKh + byo);
      bLf[nq] = *(const bf16x8*)((const char*)sKl + byo);
    }
#pragma unroll
    for (int mq = 0; mq < 2; ++mq)
#pragma unroll
      for (int nq = 0; nq < 2; ++nq) {
        acc[mq][nq] = __builtin_amdgcn_mfma_f32_32x32x16_bf16(aH[mq], bHf[nq], acc[mq][nq], 0, 0, 0);
        acc[mq][nq] = __builtin_amdgcn_mfma_f32_32x32x16_bf16(aH[mq], bLf[nq], acc[mq][nq], 0, 0, 0);
        acc[mq][nq] = __builtin_amdgcn_mfma_f32_32x32x16_bf16(aL[mq], bHf[nq], acc[mq][nq], 0, 0, 0);
      }
  }

  // epilogue: scale+mask+store + per-row (64-col strip) max/sumexp partials
  const int c0 = k0 + wn * 64 + l31;
  const int mk0 = mask[b * S + c0];
  const int mk1 = mask[b * S + c0 + 32];
  float* sm = (float*)sQh;        // [128][2] per-row per-wavecol partial max
  float* sl = sm + 256;           // [128][2] partial sumexp
  __syncthreads();                // all LDS tile reads done; safe to alias

#pragma unroll
  for (int mq = 0; mq < 2; ++mq) {
#pragma unroll
    for (int reg = 0; reg < 16; ++reg) {
      const int rloc = wm * 64 + mq * 32 + (reg & 3) + 8 * (reg >> 2) + 4 * g;
      const float v0 = mk0 ? acc[mq][0][reg] * 0.125f : -1e9f;
      const float v1 = mk1 ? acc[mq][1][reg] * 0.125f : -1e9f;
      float* dst = &attn[((size_t)bh * S + q0 + rloc) * S + (k0 + wn * 64) + l31];
      dst[0]  = v0;
      dst[32] = v1;
      float m = fmaxf(v0, v1);
#pragma unroll
      for (int off = 16; off > 0; off >>= 1) m = fmaxf(m, __shfl_xor(m, off));
      float e = __expf(v0 - m) + __expf(v1 - m);
#pragma unroll
      for (int off = 16; off > 0; off >>= 1) e += __shfl_xor(e, off);
      if (l31 == 0) { sm[rloc * 2 + wn] = m; sl[rloc * 2 + wn] = e; }
    }
  }
  __syncthreads();
  if (tid < 128) {
    const float m0 = sm[tid * 2], m1 = sm[tid * 2 + 1];
    const float l0 = sl[tid * 2], l1 = sl[tid * 2 + 1];
    const float m = fmaxf(m0, m1);
    const float l = l0 * __expf(m0 - m) + l1 * __expf(m1 - m);
    const size_t pr = ((size_t)bh * S + q0 + tid) * KT + blockIdx.y;
    Mp[pr] = m;
    Lp[pr] = l;
  }
}

// ---------------- merge 16 per-tile partials per row -> Mrow, Linv ----------
__global__ __launch_bounds__(256) void mlreduce_kernel(
    const float* __restrict__ Mp, const float* __restrict__ Lp,
    float* __restrict__ Mrow, float* __restrict__ Linv)
{
  const int r = (int)blockIdx.x * 256 + threadIdx.x;   // BH*S rows
  float mp[KT], lp[KT];
#pragma unroll
  for (int i = 0; i < KT / 4; ++i) {
    *(float4*)&mp[i * 4] = *(const float4*)&Mp[(size_t)r * KT + i * 4];
    *(float4*)&lp[i * 4] = *(const float4*)&Lp[(size_t)r * KT + i * 4];
  }
  float m = mp[0];
#pragma unroll
  for (int i = 1; i < KT; ++i) m = fmaxf(m, mp[i]);
  float l = 0.0f;
#pragma unroll
  for (int i = 0; i < KT; ++i) l += lp[i] * __expf(mp[i] - m);
  Mrow[r] = m;
  Linv[r] = 1.0f / l;
}

// ---------------- context: normalize attn in-place + C = P@V ----------------
__global__ __launch_bounds__(256, 3) void context_kernel(
    float* __restrict__ attn, const float* __restrict__ V,
    const float* __restrict__ Mrow, const float* __restrict__ Linv,
    float* __restrict__ C)
{
  __shared__ float Ps[64][128];   // Ps[k][q]
  __shared__ float Vs[64][64];    // Vs[k][d]
  const int tid = threadIdx.x;
  const int tx = tid & 15, ty = tid >> 4;
  const int q0 = blockIdx.x * 128;
  const int bh = (int)blockIdx.z, b = bh >> 3, h = bh & 7;
  float* __restrict__ A = attn + (size_t)bh * S * S;
  const float* __restrict__ Vh = V + (size_t)bh * S * DK;

  const int rq4 = (tid & 31) * 4;   // P row-quad 0..124
  const int ch  = (tid >> 5) * 4;   // P col-quad 0..28
  float mr[4], il[4];
#pragma unroll
  for (int rr = 0; rr < 4; ++rr) {
    mr[rr] = Mrow[(size_t)bh * S + q0 + rq4 + rr];
    il[rr] = Linv[(size_t)bh * S + q0 + rq4 + rr];
  }

  float acc[2][4][4] = {};   // [qhalf][qi][dj]
  const int qa = ty * 4, da = tx * 4;

  for (int k0 = 0; k0 < S; k0 += 64) {
    __syncthreads();   // previous iteration's LDS reads done
    // stage P: load raw, normalize, write back in place, transpose into LDS
#pragma unroll
    for (int half = 0; half < 64; half += 32) {
      const int cd4 = ch + half;
      float4 pr[4];
#pragma unroll
      for (int rr = 0; rr < 4; ++rr) {
        float* __restrict__ ap = &A[(size_t)(q0 + rq4 + rr) * S + k0 + cd4];
        float4 v = *(const float4*)ap;
        v.x = __expf(v.x - mr[rr]) * il[rr];
        v.y = __expf(v.y - mr[rr]) * il[rr];
        v.z = __expf(v.z - mr[rr]) * il[rr];
        v.w = __expf(v.w - mr[rr]) * il[rr];
        *(float4*)ap = v;   // final attention output
        pr[rr] = v;
      }
#pragma unroll
      for (int j = 0; j < 4; ++j)
        *(float4*)&Ps[cd4 + j][rq4] =
            make_float4(f4c(pr[0], j), f4c(pr[1], j), f4c(pr[2], j), f4c(pr[3], j));
    }
    // stage V (natural layout, coalesced)
#pragma unroll
    for (int jj = 0; jj < 4; ++jj) {
      const int r = ty + 16 * jj;
      *(float4*)&Vs[r][da] = *(const float4*)&Vh[(size_t)(k0 + r) * DK + da];
    }
    __syncthreads();
#pragma unroll 8
    for (int k = 0; k < 64; ++k) {
      const float4 a0 = *(const float4*)&Ps[k][qa];
      const float4 a1 = *(const float4*)&Ps[k][64 + qa];
      const float4 bv = *(const float4*)&Vs[k][da];
      fma4x4(acc[0], a0, bv);
      fma4x4(acc[1], a1, bv);
    }
  }

#pragma unroll
  for (int qh = 0; qh < 2; ++qh)
#pragma unroll
    for (int i = 0; i < 4; ++i) {
      const int q = q0 + qh * 64 + qa + i;
      *(float4*)&C[((size_t)(b * S + q)) * D + h * DK + da] =
          make_float4(acc[qh][i][0], acc[qh][i][1], acc[qh][i][2], acc[qh][i][3]);
    }
}

extern "C" void kernel_launch(void* const* d_in, const int* in_sizes, int n_in,
                              void* d_out, int out_size, void* d_ws, size_t ws_size,
                              hipStream_t stream)
{
  (void)in_sizes; (void)n_in; (void)out_size; (void)ws_size;
  const float* query = (const float*)d_in[0];
  const float* key   = (const float*)d_in[1];
  const float* value = (const float*)d_in[2];
  const int*   mask  = (const int*)d_in[3];
  // d_in[4] = is_organic (unused: cancels in softmax)
  const float* Wq = (const float*)d_in[5];
  const float* bq = (const float*)d_in[6];
  const float* Wk = (const float*)d_in[7];
  const float* bk = (const float*)d_in[8];
  const float* Wv = (const float*)d_in[9];
  const float* bv = (const float*)d_in[10];
  const float* Wo = (const float*)d_in[11];
  const float* bo = (const float*)d_in[12];
  // d_in[13]=Worg, d_in[14]=borg (unused: cancel in softmax)

  float* out  = (float*)d_out;
  float* attn = out + (size_t)N * D;

  // ws: bf16 Q/K hi/lo (8 MB each) + fp32 V + fp32 C = 64 MB
  ushort* Qh = (ushort*)d_ws;
  ushort* Ql = Qh + (size_t)N * D;
  ushort* Kh = Ql + (size_t)N * D;
  ushort* Kl = Kh + (size_t)N * D;
  float*  Vb = (float*)(Kl + (size_t)N * D);
  float*  Cb = Vb + (size_t)N * D;

  // scratch inside the out region (16.77 MB): Mp 4MB | Lp 4MB | Mrow | Linv.
  // Final projection overwrites all of `out` afterwards.
  float* Mp   = out;
  float* Lp   = Mp + (size_t)BH * S * KT;
  float* Mrow = Lp + (size_t)BH * S * KT;
  float* Linv = Mrow + (size_t)BH * S;

  const dim3 blk(256);
  proj_kernel<<<dim3(N / 64, D / 128), blk, 0, stream>>>(query, Wq, bq, nullptr, Qh, Ql, 2);
  proj_kernel<<<dim3(N / 64, D / 128), blk, 0, stream>>>(key,   Wk, bk, nullptr, Kh, Kl, 2);
  proj_kernel<<<dim3(N / 64, D / 128), blk, 0, stream>>>(value, Wv, bv, Vb, nullptr, nullptr, 1);
  scores_kernel<<<dim3(S / 128, S / 128, BH), blk, 0, stream>>>(Qh, Ql, Kh, Kl, mask, attn, Mp, Lp);
  mlreduce_kernel<<<dim3(BH * S / 256), blk, 0, stream>>>(Mp, Lp, Mrow, Linv);
  context_kernel<<<dim3(S / 128, 1, BH), blk, 0, stream>>>(attn, Vb, Mrow, Linv, Cb);
  proj_kernel<<<dim3(N / 64, D / 128), blk, 0, stream>>>(Cb, Wo, bo, out, nullptr, nullptr, 0);
}